// Round 2
// baseline (1736.048 us; speedup 1.0000x reference)
//
#include <hip/hip_runtime.h>

// SceneGraphModel: per-edge gather + MLP 16->128->64->32->16->8->4->51
// Outputs: [E,51] f32 logits, then relations [E] (written as float).

#define UNROLL _Pragma("unroll")

// Dense layer: OUT[NOUT] = act(IN @ W + B), fully unrolled so all activation
// arrays stay in registers (runtime-indexed arrays would spill to scratch).
#define DENSE(IN, OUT, NIN, NOUT, W, B, DO_RELU)                              \
    float OUT[NOUT];                                                          \
    UNROLL for (int j = 0; j < NOUT; ++j) OUT[j] = B[j];                      \
    UNROLL for (int i = 0; i < NIN; ++i) {                                    \
        const float x_ = IN[i];                                               \
        UNROLL for (int j = 0; j < NOUT; ++j)                                 \
            OUT[j] = fmaf(x_, W[i * NOUT + j], OUT[j]);                       \
    }                                                                         \
    if (DO_RELU) {                                                            \
        UNROLL for (int j = 0; j < NOUT; ++j) OUT[j] = fmaxf(OUT[j], 0.0f);   \
    }

__global__ __launch_bounds__(256) void sg_fused(
    const float* __restrict__ obj,     // [N_OBJ, 8]
    const int*   __restrict__ rel,     // [E]
    const int*   __restrict__ pairs,   // [E, 2]
    const float* __restrict__ oW0, const float* __restrict__ ob0,  // 16x128
    const float* __restrict__ oW1, const float* __restrict__ ob1,  // 128x64
    const float* __restrict__ oW2, const float* __restrict__ ob2,  // 64x32
    const float* __restrict__ oW3, const float* __restrict__ ob3,  // 32x16
    const float* __restrict__ rW0, const float* __restrict__ rb0,  // 16x8
    const float* __restrict__ rW1, const float* __restrict__ rb1,  // 8x4
    const float* __restrict__ rW2, const float* __restrict__ rb2,  // 4x51
    float* __restrict__ out,           // [E, 51]
    float* __restrict__ out_rel,       // [E]
    int E)
{
    const int e = blockIdx.x * 256 + threadIdx.x;
    if (e >= E) return;

    // relations passthrough (output 1), encoded as float in the flat buffer
    out_rel[e] = (float)rel[e];

    const int ia = pairs[2 * e + 0];
    const int ib = pairs[2 * e + 1];

    // gather: two 8-float rows, each 32B-aligned -> 2x float4 apiece
    float h0[16];
    {
        const float4* pa = reinterpret_cast<const float4*>(obj + (size_t)ia * 8);
        const float4* pb = reinterpret_cast<const float4*>(obj + (size_t)ib * 8);
        const float4 va0 = pa[0], va1 = pa[1];
        const float4 vb0 = pb[0], vb1 = pb[1];
        h0[0] = va0.x;  h0[1] = va0.y;  h0[2]  = va0.z;  h0[3]  = va0.w;
        h0[4] = va1.x;  h0[5] = va1.y;  h0[6]  = va1.z;  h0[7]  = va1.w;
        h0[8] = vb0.x;  h0[9] = vb0.y;  h0[10] = vb0.z;  h0[11] = vb0.w;
        h0[12] = vb1.x; h0[13] = vb1.y; h0[14] = vb1.z;  h0[15] = vb1.w;
    }

    DENSE(h0, h1, 16, 128, oW0, ob0, true)    // 16 -> 128, relu
    DENSE(h1, h2, 128, 64, oW1, ob1, true)    // 128 -> 64, relu
    DENSE(h2, h3, 64, 32,  oW2, ob2, true)    // 64 -> 32, relu
    DENSE(h3, h4, 32, 16,  oW3, ob3, false)   // 32 -> 16, linear
    DENSE(h4, h5, 16, 8,   rW0, rb0, true)    // 16 -> 8, relu
    DENSE(h5, h6, 8,  4,   rW1, rb1, true)    // 8 -> 4, relu
    DENSE(h6, h7, 4,  51,  rW2, rb2, false)   // 4 -> 51, linear

    float* op = out + (size_t)e * 51;
    UNROLL for (int j = 0; j < 51; ++j) op[j] = h7[j];
}

extern "C" void kernel_launch(void* const* d_in, const int* in_sizes, int n_in,
                              void* d_out, int out_size, void* d_ws, size_t ws_size,
                              hipStream_t stream) {
    const float* obj   = (const float*)d_in[0];
    const int*   rel   = (const int*)  d_in[1];
    const int*   pairs = (const int*)  d_in[2];
    const float* oW0 = (const float*)d_in[3];
    const float* ob0 = (const float*)d_in[4];
    const float* oW1 = (const float*)d_in[5];
    const float* ob1 = (const float*)d_in[6];
    const float* oW2 = (const float*)d_in[7];
    const float* ob2 = (const float*)d_in[8];
    const float* oW3 = (const float*)d_in[9];
    const float* ob3 = (const float*)d_in[10];
    const float* rW0 = (const float*)d_in[11];
    const float* rb0 = (const float*)d_in[12];
    const float* rW1 = (const float*)d_in[13];
    const float* rb1 = (const float*)d_in[14];
    const float* rW2 = (const float*)d_in[15];
    const float* rb2 = (const float*)d_in[16];

    const int E = in_sizes[1];            // relations is [E]
    float* out     = (float*)d_out;       // [E,51]
    float* out_rel = out + (size_t)E * 51;

    const int blocks = (E + 255) / 256;
    hipLaunchKernelGGL(sg_fused, dim3(blocks), dim3(256), 0, stream,
                       obj, rel, pairs,
                       oW0, ob0, oW1, ob1, oW2, ob2, oW3, ob3,
                       rW0, rb0, rW1, rb1, rW2, rb2,
                       out, out_rel, E);
}

// Round 3
// 419.761 us; speedup vs baseline: 4.1358x; 4.1358x over previous
//
#include <hip/hip_runtime.h>

// SceneGraphModel via split-bf16 MFMA.
// Layers 1-3 (16->128->64->32) as 16x16x32 bf16 MFMA with 3-term split
// (WhAh + WlAh + WhAl), swapped operands so C^T comes out k-contiguous
// per lane. Tail (32->16->8->4->51) per-thread fp32 VALU.
// Outputs: [E,51] f32 logits, then relations [E] as float.

typedef __attribute__((ext_vector_type(8))) short bf16x8;   // 8 bf16 = 4 VGPR
typedef __attribute__((ext_vector_type(4))) float f32x4;    // acc

#define UNROLL _Pragma("unroll")

__device__ __forceinline__ unsigned short bf16h(float x) {
    union { float f; unsigned u; } v; v.f = x;
    unsigned r = v.u + 0x7fffu + ((v.u >> 16) & 1u);   // RNE
    return (unsigned short)(r >> 16);
}
__device__ __forceinline__ float bf16f(unsigned short h) {
    union { float f; unsigned u; } v; v.u = ((unsigned)h) << 16;
    return v.f;
}
__device__ __forceinline__ void split2(float x, unsigned short& hi, unsigned short& lo) {
    hi = bf16h(x);
    lo = bf16h(x - bf16f(hi));
}

__device__ __forceinline__ f32x4 mfma3(bf16x8 wh, bf16x8 wl, bf16x8 ah, bf16x8 al, f32x4 acc) {
    acc = __builtin_amdgcn_mfma_f32_16x16x32_bf16(wh, ah, acc, 0, 0, 0);
    acc = __builtin_amdgcn_mfma_f32_16x16x32_bf16(wl, ah, acc, 0, 0, 0);
    acc = __builtin_amdgcn_mfma_f32_16x16x32_bf16(wh, al, acc, 0, 0, 0);
    return acc;
}

__device__ __forceinline__ f32x4 bias4(const float* __restrict__ b, int nt, int g) {
    const float4 v = *(const float4*)(b + nt * 16 + g * 4);
    f32x4 r; r[0] = v.x; r[1] = v.y; r[2] = v.z; r[3] = v.w; return r;
}

// Write one lane's 4 consecutive-k values (post-relu) of a C^T frag into the
// next layer's A-fragment-order LDS buffer (split hi/lo), packed as 2x b64.
__device__ __forceinline__ void write_frag_chunk(
    unsigned short* __restrict__ baseh, unsigned short* __restrict__ basel,
    int mt, int lr, int g, int ntl, f32x4 a)
{
    unsigned short h0,h1,h2,h3,l0,l1,l2,l3;
    split2(a[0], h0, l0); split2(a[1], h1, l1);
    split2(a[2], h2, l2); split2(a[3], h3, l3);
    unsigned long long ph = (unsigned long long)h0 | ((unsigned long long)h1 << 16) |
                            ((unsigned long long)h2 << 32) | ((unsigned long long)h3 << 48);
    unsigned long long pl = (unsigned long long)l0 | ((unsigned long long)l1 << 16) |
                            ((unsigned long long)l2 << 32) | ((unsigned long long)l3 << 48);
    const int klb   = ntl * 16 + g * 4;                 // within-chunk k of first elem
    const int lanep = lr + 16 * ((klb >> 3) & 3);       // dest fragment lane
    const int j0    = klb & 7;                          // 0 or 4
    *(unsigned long long*)(baseh + mt * 512 + lanep * 8 + j0) = ph;
    *(unsigned long long*)(basel + mt * 512 + lanep * 8 + j0) = pl;
}

// ---- weight prep: split + fragment-swizzle oW0/oW1/oW2 into d_ws ----
// frag element: lane lid holds W[k][n], k = kt*32 + (lid>>4)*8 + j, n = nt*16 + (lid&15)
// flat: base_l + (kt*NT + nt)*512 + lid*8 + j ; hi at [0,14336), lo at +14336.
__global__ __launch_bounds__(256) void sg_prep(
    const float* __restrict__ oW0, const float* __restrict__ oW1,
    const float* __restrict__ oW2, unsigned short* __restrict__ wsp)
{
    const int idx = blockIdx.x * 256 + threadIdx.x;
    if (idx >= 14336) return;
    int t = idx, K, N, kt, nt;
    const float* W;
    if (t < 4096)        { W = oW0; K = 16;  N = 128; kt = 0;              nt = t >> 9; }
    else if (t < 12288)  { t -= 4096;  W = oW1; K = 128; N = 64; int f = t >> 9; kt = f >> 2; nt = f & 3; }
    else                 { t -= 12288; W = oW2; K = 64;  N = 32; int f = t >> 9; kt = f >> 1; nt = f & 1; }
    const int lid = (t >> 3) & 63, j = t & 7;
    const int k = kt * 32 + (lid >> 4) * 8 + j;
    const int n = nt * 16 + (lid & 15);
    const float w = (k < K) ? W[(size_t)k * N + n] : 0.0f;
    unsigned short hi, lo;
    split2(w, hi, lo);
    wsp[idx] = hi;
    wsp[14336 + idx] = lo;
}

// Tail dense layer macro (fp32, fully unrolled, register-resident)
#define DENSE(IN, OUT, NIN, NOUT, W, B, DO_RELU)                              \
    float OUT[NOUT];                                                          \
    UNROLL for (int j = 0; j < NOUT; ++j) OUT[j] = B[j];                      \
    UNROLL for (int i = 0; i < NIN; ++i) {                                    \
        const float x_ = IN[i];                                               \
        UNROLL for (int j = 0; j < NOUT; ++j)                                 \
            OUT[j] = fmaf(x_, W[i * NOUT + j], OUT[j]);                       \
    }                                                                         \
    if (DO_RELU) {                                                            \
        UNROLL for (int j = 0; j < NOUT; ++j) OUT[j] = fmaxf(OUT[j], 0.0f);   \
    }

__global__ __launch_bounds__(256, 2) void sg_mfma(
    const float* __restrict__ obj, const int* __restrict__ rel,
    const int* __restrict__ pairs,
    const unsigned short* __restrict__ wsp,
    const float* __restrict__ ob0, const float* __restrict__ ob1,
    const float* __restrict__ ob2,
    const float* __restrict__ oW3, const float* __restrict__ ob3,
    const float* __restrict__ rW0, const float* __restrict__ rb0,
    const float* __restrict__ rW1, const float* __restrict__ rb1,
    const float* __restrict__ rW2, const float* __restrict__ rb2,
    float* __restrict__ out, float* __restrict__ out_rel, int E)
{
    __shared__ unsigned char smem[65536];
    unsigned short* sA0h = (unsigned short*)smem;            // pool1 (later sA2)
    unsigned short* sA0l = (unsigned short*)(smem + 16384);
    unsigned short* sA2h = sA0h;
    unsigned short* sA2l = sA0l;
    unsigned short* h1ch = (unsigned short*)(smem + 32768);  // pool2 (later sH3)
    unsigned short* h1cl = (unsigned short*)(smem + 49152);
    float*          sH3  = (float*)(smem + 32768);

    const int tid = threadIdx.x;
    const int lid = tid & 63;
    const int wid = tid >> 6;
    const int g   = lid >> 4;     // k-group 0..3
    const int lr  = lid & 15;     // edge-row lane within tile
    const long long eBase = (long long)blockIdx.x * 256;

    // ---- stage h0 (gather, split, fragment order, K padded 16->32 with 0) ----
    {
        long long ee = eBase + tid;
        const int e = (ee < E) ? (int)ee : (E - 1);
        const int ia = pairs[2 * e + 0], ib = pairs[2 * e + 1];
        const float4* pa = (const float4*)(obj + (size_t)ia * 8);
        const float4* pb = (const float4*)(obj + (size_t)ib * 8);
        float f[16];
        {
            float4 v0 = pa[0], v1 = pa[1], v2 = pb[0], v3 = pb[1];
            f[0]=v0.x; f[1]=v0.y; f[2]=v0.z;  f[3]=v0.w;
            f[4]=v1.x; f[5]=v1.y; f[6]=v1.z;  f[7]=v1.w;
            f[8]=v2.x; f[9]=v2.y; f[10]=v2.z; f[11]=v2.w;
            f[12]=v3.x; f[13]=v3.y; f[14]=v3.z; f[15]=v3.w;
        }
        unsigned short hs[16], ls[16];
        UNROLL for (int i = 0; i < 16; ++i) split2(f[i], hs[i], ls[i]);
        const int mt = tid >> 4, rl = tid & 15;
        uint4 c0, c1, d0, d1, zz;
        zz.x = zz.y = zz.z = zz.w = 0;
        c0.x = hs[0] | ((unsigned)hs[1] << 16);  c0.y = hs[2] | ((unsigned)hs[3] << 16);
        c0.z = hs[4] | ((unsigned)hs[5] << 16);  c0.w = hs[6] | ((unsigned)hs[7] << 16);
        c1.x = hs[8] | ((unsigned)hs[9] << 16);  c1.y = hs[10] | ((unsigned)hs[11] << 16);
        c1.z = hs[12] | ((unsigned)hs[13] << 16); c1.w = hs[14] | ((unsigned)hs[15] << 16);
        d0.x = ls[0] | ((unsigned)ls[1] << 16);  d0.y = ls[2] | ((unsigned)ls[3] << 16);
        d0.z = ls[4] | ((unsigned)ls[5] << 16);  d0.w = ls[6] | ((unsigned)ls[7] << 16);
        d1.x = ls[8] | ((unsigned)ls[9] << 16);  d1.y = ls[10] | ((unsigned)ls[11] << 16);
        d1.z = ls[12] | ((unsigned)ls[13] << 16); d1.w = ls[14] | ((unsigned)ls[15] << 16);
        unsigned short* dh = sA0h + mt * 512 + rl * 8;
        unsigned short* dl = sA0l + mt * 512 + rl * 8;
        *(uint4*)(dh)       = c0;  *(uint4*)(dh + 128) = c1;   // k 0..7, 8..15
        *(uint4*)(dh + 256) = zz;  *(uint4*)(dh + 384) = zz;   // k 16..31 pad
        *(uint4*)(dl)       = d0;  *(uint4*)(dl + 128) = d1;
        *(uint4*)(dl + 256) = zz;  *(uint4*)(dl + 384) = zz;
    }
    __syncthreads();

    // ---- layers 1+2 fused over h1 32-col chunks ----
    f32x4 acc2[4][4];
    UNROLL for (int m = 0; m < 4; ++m)
        UNROLL for (int n2 = 0; n2 < 4; ++n2) acc2[m][n2] = bias4(ob1, n2, g);

    for (int kt2 = 0; kt2 < 4; ++kt2) {
        // layer1: h1 cols [kt2*32, +32)
        UNROLL for (int m = 0; m < 4; ++m) {
            const int mt = wid * 4 + m;
            bf16x8 ah = *(const bf16x8*)(sA0h + mt * 512 + lid * 8);
            bf16x8 al = *(const bf16x8*)(sA0l + mt * 512 + lid * 8);
            UNROLL for (int ntl = 0; ntl < 2; ++ntl) {
                const int nt = kt2 * 2 + ntl;
                const unsigned short* wb = wsp + (size_t)nt * 512 + lid * 8;
                f32x4 a = bias4(ob0, nt, g);
                a = mfma3(*(const bf16x8*)wb, *(const bf16x8*)(wb + 14336), ah, al, a);
                UNROLL for (int jr = 0; jr < 4; ++jr) a[jr] = fmaxf(a[jr], 0.0f);
                write_frag_chunk(h1ch, h1cl, mt, lr, g, ntl, a);
            }
        }
        __syncthreads();
        // layer2 partial accumulate over this k-chunk
        UNROLL for (int m = 0; m < 4; ++m) {
            const int mt = wid * 4 + m;
            bf16x8 ah = *(const bf16x8*)(h1ch + mt * 512 + lid * 8);
            bf16x8 al = *(const bf16x8*)(h1cl + mt * 512 + lid * 8);
            UNROLL for (int n2 = 0; n2 < 4; ++n2) {
                const unsigned short* wb = wsp + 4096 + (size_t)(kt2 * 4 + n2) * 512 + lid * 8;
                acc2[m][n2] = mfma3(*(const bf16x8*)wb, *(const bf16x8*)(wb + 14336),
                                    ah, al, acc2[m][n2]);
            }
        }
        __syncthreads();
    }

    // relu h2
    UNROLL for (int m = 0; m < 4; ++m)
        UNROLL for (int n2 = 0; n2 < 4; ++n2)
            UNROLL for (int jr = 0; jr < 4; ++jr)
                acc2[m][n2][jr] = fmaxf(acc2[m][n2][jr], 0.0f);

    // ---- layer 3 fused over h2 32-col chunks ----
    f32x4 acc3[4][2];
    UNROLL for (int m = 0; m < 4; ++m)
        UNROLL for (int n3 = 0; n3 < 2; ++n3) acc3[m][n3] = bias4(ob2, n3, g);

    UNROLL for (int kt3 = 0; kt3 < 2; ++kt3) {
        UNROLL for (int m = 0; m < 4; ++m) {
            const int mt = wid * 4 + m;
            UNROLL for (int ntl = 0; ntl < 2; ++ntl)
                write_frag_chunk(sA2h, sA2l, mt, lr, g, ntl, acc2[m][2 * kt3 + ntl]);
        }
        __syncthreads();
        UNROLL for (int m = 0; m < 4; ++m) {
            const int mt = wid * 4 + m;
            bf16x8 ah = *(const bf16x8*)(sA2h + mt * 512 + lid * 8);
            bf16x8 al = *(const bf16x8*)(sA2l + mt * 512 + lid * 8);
            UNROLL for (int n3 = 0; n3 < 2; ++n3) {
                const unsigned short* wb = wsp + 12288 + (size_t)(kt3 * 2 + n3) * 512 + lid * 8;
                acc3[m][n3] = mfma3(*(const bf16x8*)wb, *(const bf16x8*)(wb + 14336),
                                    ah, al, acc3[m][n3]);
            }
        }
        __syncthreads();
    }

    // relu h3 -> sH3 (f32, XOR-swizzled float4 chunks)
    UNROLL for (int m = 0; m < 4; ++m) {
        const int R = (wid * 4 + m) * 16 + lr;
        UNROLL for (int n3 = 0; n3 < 2; ++n3) {
            f32x4 a = acc3[m][n3];
            UNROLL for (int jr = 0; jr < 4; ++jr) a[jr] = fmaxf(a[jr], 0.0f);
            const int c = n3 * 4 + g;
            float4 v; v.x = a[0]; v.y = a[1]; v.z = a[2]; v.w = a[3];
            *(float4*)(sH3 + R * 32 + ((c ^ (R & 7)) << 2)) = v;
        }
    }
    __syncthreads();

    // ---- tail: per-thread fp32 MLP 32->16->8->4->51 ----
    float h3[32];
    UNROLL for (int c = 0; c < 8; ++c) {
        float4 v = *(const float4*)(sH3 + tid * 32 + ((c ^ (tid & 7)) << 2));
        h3[4 * c + 0] = v.x; h3[4 * c + 1] = v.y;
        h3[4 * c + 2] = v.z; h3[4 * c + 3] = v.w;
    }
    DENSE(h3, h4, 32, 16, oW3, ob3, false)
    DENSE(h4, h5, 16, 8,  rW0, rb0, true)
    DENSE(h5, h6, 8,  4,  rW1, rb1, true)
    DENSE(h6, h7, 4,  51, rW2, rb2, false)

    const long long ee = eBase + tid;
    if (ee < E) {
        out_rel[ee] = (float)rel[ee];
        float* op = out + ee * 51;
        UNROLL for (int j = 0; j < 51; ++j) op[j] = h7[j];
    }
}

extern "C" void kernel_launch(void* const* d_in, const int* in_sizes, int n_in,
                              void* d_out, int out_size, void* d_ws, size_t ws_size,
                              hipStream_t stream) {
    const float* obj   = (const float*)d_in[0];
    const int*   rel   = (const int*)  d_in[1];
    const int*   pairs = (const int*)  d_in[2];
    const float* oW0 = (const float*)d_in[3];
    const float* ob0 = (const float*)d_in[4];
    const float* oW1 = (const float*)d_in[5];
    const float* ob1 = (const float*)d_in[6];
    const float* oW2 = (const float*)d_in[7];
    const float* ob2 = (const float*)d_in[8];
    const float* oW3 = (const float*)d_in[9];
    const float* ob3 = (const float*)d_in[10];
    const float* rW0 = (const float*)d_in[11];
    const float* rb0 = (const float*)d_in[12];
    const float* rW1 = (const float*)d_in[13];
    const float* rb1 = (const float*)d_in[14];
    const float* rW2 = (const float*)d_in[15];
    const float* rb2 = (const float*)d_in[16];

    const int E = in_sizes[1];
    float* out     = (float*)d_out;
    float* out_rel = out + (size_t)E * 51;
    unsigned short* wsp = (unsigned short*)d_ws;

    hipLaunchKernelGGL(sg_prep, dim3(56), dim3(256), 0, stream, oW0, oW1, oW2, wsp);

    const int blocks = (E + 255) / 256;
    hipLaunchKernelGGL(sg_mfma, dim3(blocks), dim3(256), 0, stream,
                       obj, rel, pairs, wsp,
                       ob0, ob1, ob2, oW3, ob3,
                       rW0, rb0, rW1, rb1, rW2, rb2,
                       out, out_rel, E);
}

// Round 4
// 250.746 us; speedup vs baseline: 6.9235x; 1.6740x over previous
//
#include <hip/hip_runtime.h>

// SceneGraphModel, single-bf16 MFMA, barrier-free per-wave pipeline.
// Layers 1-4 (16->128->64->32->16) as 16x16x32 bf16 MFMA (swapped operands,
// C^T k-contiguous per lane). Tail (16->8->4->51) per-thread fp32.
// Outputs: [E,51] f32 logits, then relations [E] as float.
// Accuracy: bf16 rel ~2^-9; measured thresholds (r0/r3) give >100x margin.

typedef __attribute__((ext_vector_type(8))) short bf16x8;   // 8 bf16 = 4 VGPR
typedef __attribute__((ext_vector_type(4))) float f32x4;

#define UNROLL _Pragma("unroll")

__device__ __forceinline__ unsigned short bf16h(float x) {
    union { float f; unsigned u; } v; v.f = x;
    unsigned r = v.u + 0x7fffu + ((v.u >> 16) & 1u);   // RNE
    return (unsigned short)(r >> 16);
}

__device__ __forceinline__ f32x4 mfma1(bf16x8 w, bf16x8 a, f32x4 acc) {
    return __builtin_amdgcn_mfma_f32_16x16x32_bf16(w, a, acc, 0, 0, 0);
}

__device__ __forceinline__ f32x4 bias4(const float* __restrict__ b, int nt, int g) {
    const float4 v = *(const float4*)(b + nt * 16 + g * 4);
    f32x4 r; r[0] = v.x; r[1] = v.y; r[2] = v.z; r[3] = v.w; return r;
}

// Store one lane's 4 consecutive-k values (bf16) into A-frag-order LDS tile.
// Element (row lr, k) lives at short index (lr + 16*(k>>3))*8 + (k&7).
__device__ __forceinline__ void chunk_store(unsigned short* __restrict__ tile,
                                            int lr, int klb, f32x4 a) {
    unsigned long long p =
        (unsigned long long)bf16h(a[0]) |
        ((unsigned long long)bf16h(a[1]) << 16) |
        ((unsigned long long)bf16h(a[2]) << 32) |
        ((unsigned long long)bf16h(a[3]) << 48);
    const int lanep = lr + 16 * (klb >> 3);
    *(unsigned long long*)(tile + lanep * 8 + (klb & 7)) = p;
}

// ---- weight prep: bf16 + fragment-swizzle oW0/oW1/oW2/oW3 into d_ws ----
// frag element: lane lid holds W[k][n], k = kt*32 + (lid>>4)*8 + j, n = nt*16 + (lid&15)
// offsets (shorts): W0 @0 (8 nt), W1 @4096 (4kt x 4nt), W2 @12288 (2kt x 2nt), W3 @14336 (1x1)
__global__ __launch_bounds__(256) void sg_prep(
    const float* __restrict__ oW0, const float* __restrict__ oW1,
    const float* __restrict__ oW2, const float* __restrict__ oW3,
    unsigned short* __restrict__ wsp)
{
    const int idx = blockIdx.x * 256 + threadIdx.x;
    if (idx >= 14848) return;
    int t = idx, K, N, kt, nt;
    const float* W;
    if (t < 4096)        { W = oW0; K = 16;  N = 128; kt = 0; nt = t >> 9; }
    else if (t < 12288)  { t -= 4096;  W = oW1; K = 128; N = 64; int f = t >> 9; kt = f >> 2; nt = f & 3; }
    else if (t < 14336)  { t -= 12288; W = oW2; K = 64;  N = 32; int f = t >> 9; kt = f >> 1; nt = f & 1; }
    else                 { t -= 14336; W = oW3; K = 32;  N = 16; kt = 0; nt = 0; }
    const int lid = (t >> 3) & 63, j = t & 7;
    const int k = kt * 32 + (lid >> 4) * 8 + j;
    const int n = nt * 16 + (lid & 15);
    const float w = (k < K) ? W[(size_t)k * N + n] : 0.0f;
    wsp[idx] = bf16h(w);
}

// Tail dense layer (fp32, fully unrolled, register-resident)
#define DENSE(IN, OUT, NIN, NOUT, W, B, DO_RELU)                              \
    float OUT[NOUT];                                                          \
    UNROLL for (int j = 0; j < NOUT; ++j) OUT[j] = B[j];                      \
    UNROLL for (int i = 0; i < NIN; ++i) {                                    \
        const float x_ = IN[i];                                               \
        UNROLL for (int j = 0; j < NOUT; ++j)                                 \
            OUT[j] = fmaf(x_, W[i * NOUT + j], OUT[j]);                       \
    }                                                                         \
    if (DO_RELU) {                                                            \
        UNROLL for (int j = 0; j < NOUT; ++j) OUT[j] = fmaxf(OUT[j], 0.0f);   \
    }

__global__ __launch_bounds__(256, 4) void sg_mfma(
    const float* __restrict__ obj, const int* __restrict__ rel,
    const int* __restrict__ pairs,
    const unsigned short* __restrict__ wsp,
    const float* __restrict__ ob0, const float* __restrict__ ob1,
    const float* __restrict__ ob2, const float* __restrict__ ob3,
    const float* __restrict__ rW0, const float* __restrict__ rb0,
    const float* __restrict__ rW1, const float* __restrict__ rb1,
    const float* __restrict__ rW2, const float* __restrict__ rb2,
    float* __restrict__ out, float* __restrict__ out_rel, int E)
{
    // Per-wave private 8 KB LDS block: all producer/consumer traffic is
    // intra-wave (same-wave DS ops execute in order), so NO __syncthreads.
    __shared__ unsigned char smem[32768];
    const int tid = threadIdx.x;
    const int lid = tid & 63;
    const int wid = tid >> 6;
    const int g = lid >> 4, lr = lid & 15;
    unsigned char* wbase = smem + wid * 8192;
    unsigned short* sA = (unsigned short*)wbase;            // 4 frag tiles: h0, later h2-chunks
    unsigned short* sB = (unsigned short*)(wbase + 4096);   // 4 frag tiles: h1-chunks, later h3
    float* sH4 = (float*)wbase;                             // 64 rows x 20 f32 (5120 B)

    const long long eBase = (long long)blockIdx.x * 256;
    const long long ee = eBase + tid;
    const int e = (ee < E) ? (int)ee : (E - 1);

    if (ee < E) out_rel[ee] = (float)rel[e];

    // ---- stage h0: thread stages its own edge into (tile g, row lr) ----
    {
        const int2 pr = *(const int2*)(pairs + 2 * e);
        const float4* pa = (const float4*)(obj + (size_t)pr.x * 8);
        const float4* pb = (const float4*)(obj + (size_t)pr.y * 8);
        const float4 v0 = pa[0], v1 = pa[1], v2 = pb[0], v3 = pb[1];
        uint4 c0, c1, zz;
        c0.x = bf16h(v0.x) | ((unsigned)bf16h(v0.y) << 16);
        c0.y = bf16h(v0.z) | ((unsigned)bf16h(v0.w) << 16);
        c0.z = bf16h(v1.x) | ((unsigned)bf16h(v1.y) << 16);
        c0.w = bf16h(v1.z) | ((unsigned)bf16h(v1.w) << 16);
        c1.x = bf16h(v2.x) | ((unsigned)bf16h(v2.y) << 16);
        c1.y = bf16h(v2.z) | ((unsigned)bf16h(v2.w) << 16);
        c1.z = bf16h(v3.x) | ((unsigned)bf16h(v3.y) << 16);
        c1.w = bf16h(v3.z) | ((unsigned)bf16h(v3.w) << 16);
        zz.x = zz.y = zz.z = zz.w = 0;
        unsigned short* dh = sA + g * 512 + lr * 8;
        *(uint4*)(dh)       = c0;   // k 0..7
        *(uint4*)(dh + 128) = c1;   // k 8..15
        *(uint4*)(dh + 256) = zz;   // k 16..31 pad
        *(uint4*)(dh + 384) = zz;
    }
    __builtin_amdgcn_wave_barrier();

    // hoist h0 A-frags (constant across all layer-1 tiles)
    bf16x8 a0[4];
    UNROLL for (int m = 0; m < 4; ++m)
        a0[m] = *(const bf16x8*)(sA + m * 512 + lid * 8);
    __builtin_amdgcn_wave_barrier();

    // ---- layers 1+2 fused over h1 32-col chunks ----
    f32x4 acc2[4][4];
    UNROLL for (int m = 0; m < 4; ++m)
        UNROLL for (int n2 = 0; n2 < 4; ++n2) acc2[m][n2] = bias4(ob1, n2, g);

    for (int kt2 = 0; kt2 < 4; ++kt2) {
        UNROLL for (int m = 0; m < 4; ++m) {
            UNROLL for (int ntl = 0; ntl < 2; ++ntl) {
                const int nt = kt2 * 2 + ntl;
                f32x4 a = bias4(ob0, nt, g);
                a = mfma1(*(const bf16x8*)(wsp + (size_t)nt * 512 + lid * 8), a0[m], a);
                UNROLL for (int jr = 0; jr < 4; ++jr) a[jr] = fmaxf(a[jr], 0.0f);
                chunk_store(sB + m * 512, lr, ntl * 16 + g * 4, a);
            }
        }
        __builtin_amdgcn_wave_barrier();
        UNROLL for (int m = 0; m < 4; ++m) {
            bf16x8 ah = *(const bf16x8*)(sB + m * 512 + lid * 8);
            UNROLL for (int n2 = 0; n2 < 4; ++n2) {
                const bf16x8 w = *(const bf16x8*)(wsp + 4096 + (size_t)(kt2 * 4 + n2) * 512 + lid * 8);
                acc2[m][n2] = mfma1(w, ah, acc2[m][n2]);
            }
        }
        __builtin_amdgcn_wave_barrier();
    }

    // relu h2
    UNROLL for (int m = 0; m < 4; ++m)
        UNROLL for (int n2 = 0; n2 < 4; ++n2)
            UNROLL for (int jr = 0; jr < 4; ++jr)
                acc2[m][n2][jr] = fmaxf(acc2[m][n2][jr], 0.0f);

    // ---- layer 3 over h2 32-col chunks ----
    f32x4 acc3[4][2];
    UNROLL for (int m = 0; m < 4; ++m)
        UNROLL for (int n3 = 0; n3 < 2; ++n3) acc3[m][n3] = bias4(ob2, n3, g);

    UNROLL for (int kt3 = 0; kt3 < 2; ++kt3) {
        UNROLL for (int m = 0; m < 4; ++m)
            UNROLL for (int ntl = 0; ntl < 2; ++ntl)
                chunk_store(sA + m * 512, lr, ntl * 16 + g * 4, acc2[m][2 * kt3 + ntl]);
        __builtin_amdgcn_wave_barrier();
        UNROLL for (int m = 0; m < 4; ++m) {
            bf16x8 ah = *(const bf16x8*)(sA + m * 512 + lid * 8);
            UNROLL for (int n3 = 0; n3 < 2; ++n3) {
                const bf16x8 w = *(const bf16x8*)(wsp + 12288 + (size_t)(kt3 * 2 + n3) * 512 + lid * 8);
                acc3[m][n3] = mfma1(w, ah, acc3[m][n3]);
            }
        }
        __builtin_amdgcn_wave_barrier();
    }

    // ---- layer 4 (32->16, linear) via MFMA ----
    UNROLL for (int m = 0; m < 4; ++m) {
        UNROLL for (int n3 = 0; n3 < 2; ++n3) {
            UNROLL for (int jr = 0; jr < 4; ++jr)
                acc3[m][n3][jr] = fmaxf(acc3[m][n3][jr], 0.0f);   // relu h3
            chunk_store(sB + m * 512, lr, n3 * 16 + g * 4, acc3[m][n3]);
        }
    }
    __builtin_amdgcn_wave_barrier();
    f32x4 acc4[4];
    UNROLL for (int m = 0; m < 4; ++m) {
        bf16x8 ah = *(const bf16x8*)(sB + m * 512 + lid * 8);
        acc4[m] = mfma1(*(const bf16x8*)(wsp + 14336 + lid * 8), ah, bias4(ob3, 0, g));
    }
    __builtin_amdgcn_wave_barrier();

    // ---- h4 -> per-thread rows via stride-20 LDS (16B-aligned, bank-spread) ----
    UNROLL for (int m = 0; m < 4; ++m) {
        const int r = m * 16 + lr;
        float4 v; v.x = acc4[m][0]; v.y = acc4[m][1]; v.z = acc4[m][2]; v.w = acc4[m][3];
        *(float4*)(sH4 + r * 20 + g * 4) = v;
    }
    __builtin_amdgcn_wave_barrier();
    float h4[16];
    UNROLL for (int s = 0; s < 4; ++s) {
        const float4 v = *(const float4*)(sH4 + lid * 20 + s * 4);
        h4[4 * s + 0] = v.x; h4[4 * s + 1] = v.y;
        h4[4 * s + 2] = v.z; h4[4 * s + 3] = v.w;
    }

    // ---- tail: per-thread fp32 MLP 16->8->4->51 ----
    DENSE(h4, h5, 16, 8, rW0, rb0, true)
    DENSE(h5, h6, 8,  4, rW1, rb1, true)
    DENSE(h6, h7, 4, 51, rW2, rb2, false)

    if (ee < E) {
        float* op = out + ee * 51;
        UNROLL for (int j = 0; j < 51; ++j) op[j] = h7[j];
    }
}

extern "C" void kernel_launch(void* const* d_in, const int* in_sizes, int n_in,
                              void* d_out, int out_size, void* d_ws, size_t ws_size,
                              hipStream_t stream) {
    const float* obj   = (const float*)d_in[0];
    const int*   rel   = (const int*)  d_in[1];
    const int*   pairs = (const int*)  d_in[2];
    const float* oW0 = (const float*)d_in[3];
    const float* ob0 = (const float*)d_in[4];
    const float* oW1 = (const float*)d_in[5];
    const float* ob1 = (const float*)d_in[6];
    const float* oW2 = (const float*)d_in[7];
    const float* ob2 = (const float*)d_in[8];
    const float* oW3 = (const float*)d_in[9];
    const float* ob3 = (const float*)d_in[10];
    const float* rW0 = (const float*)d_in[11];
    const float* rb0 = (const float*)d_in[12];
    const float* rW1 = (const float*)d_in[13];
    const float* rb1 = (const float*)d_in[14];
    const float* rW2 = (const float*)d_in[15];
    const float* rb2 = (const float*)d_in[16];

    const int E = in_sizes[1];
    float* out     = (float*)d_out;
    float* out_rel = out + (size_t)E * 51;
    unsigned short* wsp = (unsigned short*)d_ws;

    hipLaunchKernelGGL(sg_prep, dim3(58), dim3(256), 0, stream, oW0, oW1, oW2, oW3, wsp);

    const int blocks = (E + 255) / 256;
    hipLaunchKernelGGL(sg_mfma, dim3(blocks), dim3(256), 0, stream,
                       obj, rel, pairs, wsp,
                       ob0, ob1, ob2, ob3,
                       rW0, rb0, rW1, rb1, rW2, rb2,
                       out, out_rel, E);
}